// Round 7
// baseline (541.369 us; speedup 1.0000x reference)
//
#include <hip/hip_runtime.h>

#define SEQ 4096
#define NBATCH 256

__device__ __forceinline__ float sqf(float v) { return v * v; }
__device__ __forceinline__ float fexp2(float v) { return __builtin_amdgcn_exp2f(v); }
__device__ __forceinline__ float frcp(float v)  { return __builtin_amdgcn_rcpf(v); }

#define L2E 1.4426950408889634f

// ---------------------------------------------------------------------------
// Kernel 0: fold the 24-wide input matvec into 12 inputs.
// The scatter vector vv[24] has only 12 distinct values; precompute
// W'[d][r][k] (k<12) = combined weights, W'[..][12] = bias, all scaled by
// the row's activation pre-scale sc_r (-log2e, or -2log2e for g rows).
// ---------------------------------------------------------------------------
__global__ void wprep_kernel(
    const float* __restrict__ Wih_f, const float* __restrict__ bih_f,
    const float* __restrict__ bhh_f,
    const float* __restrict__ Wih_r, const float* __restrict__ bih_r,
    const float* __restrict__ bhh_r,
    float* __restrict__ Wp)
{
    const int t = threadIdx.x;
    if (t >= 80) return;
    const int d = t / 40, r = t % 40;
    const float* __restrict__ W  = (d ? Wih_r : Wih_f) + r * 24;
    const float* __restrict__ bi = d ? bih_r : bih_f;
    const float* __restrict__ bh = d ? bhh_r : bhh_f;
    const float sc = (r >= 20 && r < 30) ? (-2.f * L2E) : (-L2E);
    float o[13];
    o[0]  = W[0] + W[1] + W[2] + W[3];                // v4s
    o[1]  = W[4] + W[5] + W[6] + W[7];                // v5s
    o[2]  = W[4];                                     // v5p
    o[3]  = W[8] + W[9] + W[10] + W[11];              // v6s
    o[4]  = W[8] + W[9];                              // v6p
    o[5]  = W[12] + W[13] + W[14] + W[15];            // v7s
    o[6]  = W[12] + W[13] + W[14];                    // v7p
    o[7]  = W[16] + W[17] + W[18] + W[19];            // v8s+v8p
    o[8]  = W[20]; o[9] = W[21]; o[10] = W[22]; o[11] = W[23];   // x0..x3
    o[12] = bi[r] + bh[r];
    float* __restrict__ out = Wp + (d * 40 + r) * 16;
#pragma unroll
    for (int k = 0; k < 13; ++k) out[k] = o[k] * sc;
    out[13] = 0.f; out[14] = 0.f; out[15] = 0.f;
}

// ---------------------------------------------------------------------------
// Kernel 1a: per-batch conv max. One block per batch row; writes MM[b][5].
// ---------------------------------------------------------------------------
__global__ __launch_bounds__(256) void max_kernel(
    const float* __restrict__ x,
    const float* __restrict__ w4p, const float* __restrict__ w5p,
    const float* __restrict__ w6p, const float* __restrict__ w7p,
    const float* __restrict__ w8p,
    float* __restrict__ MMg)
{
    const int b   = blockIdx.x;
    const int tid = threadIdx.x;
    const float* __restrict__ xr = x + (size_t)b * (4 * SEQ);

    float W4[4], W5[5], W6[6], W7[7], W8[8];
#pragma unroll
    for (int k = 0; k < 4; ++k) W4[k] = w4p[k];
#pragma unroll
    for (int k = 0; k < 5; ++k) W5[k] = w5p[k];
#pragma unroll
    for (int k = 0; k < 6; ++k) W6[k] = w6p[k];
#pragma unroll
    for (int k = 0; k < 7; ++k) W7[k] = w7p[k];
#pragma unroll
    for (int k = 0; k < 8; ++k) W8[k] = w8p[k];

    float m4 = -3.4e38f, m5 = -3.4e38f, m6 = -3.4e38f, m7 = -3.4e38f, m8 = -3.4e38f;
    for (int i = tid; i < SEQ; i += 256) {
        const float4 t0 = *reinterpret_cast<const float4*>(xr + 4 * i);
        const float xa0 = t0.x, xa1 = t0.y, xa2 = t0.z, xa3 = t0.w;
        const float c4 = xa0 * W4[0] + xa1 * W4[1] + xa2 * W4[2] + xa3 * W4[3];
        m4 = fmaxf(m4, c4);
        if (i < SEQ - 1) {
            const float4 t1 = *reinterpret_cast<const float4*>(xr + 4 * i + 4);
            const float xa4 = t1.x, xa5 = t1.y, xa6 = t1.z, xa7 = t1.w;
            const float c5 = xa0*W5[0]+xa1*W5[1]+xa2*W5[2]+xa3*W5[3]+xa4*W5[4];
            const float c6 = xa0*W6[0]+xa1*W6[1]+xa2*W6[2]+xa3*W6[3]+xa4*W6[4]+xa5*W6[5];
            const float c7 = xa0*W7[0]+xa1*W7[1]+xa2*W7[2]+xa3*W7[3]+xa4*W7[4]+xa5*W7[5]+xa6*W7[6];
            const float c8 = xa0*W8[0]+xa1*W8[1]+xa2*W8[2]+xa3*W8[3]+xa4*W8[4]+xa5*W8[5]+xa6*W8[6]+xa7*W8[7];
            m5 = fmaxf(m5, c5); m6 = fmaxf(m6, c6);
            m7 = fmaxf(m7, c7); m8 = fmaxf(m8, c8);
        }
    }
#pragma unroll
    for (int off = 32; off; off >>= 1) {
        m4 = fmaxf(m4, __shfl_down(m4, off));
        m5 = fmaxf(m5, __shfl_down(m5, off));
        m6 = fmaxf(m6, __shfl_down(m6, off));
        m7 = fmaxf(m7, __shfl_down(m7, off));
        m8 = fmaxf(m8, __shfl_down(m8, off));
    }
    __shared__ float wr[4][5];
    if ((tid & 63) == 0) {
        const int w = tid >> 6;
        wr[w][0] = m4; wr[w][1] = m5; wr[w][2] = m6; wr[w][3] = m7; wr[w][4] = m8;
    }
    __syncthreads();
    if (tid < 5)
        MMg[b * 5 + tid] = fmaxf(fmaxf(wr[0][tid], wr[1][tid]),
                                 fmaxf(wr[2][tid], wr[3][tid]));
}

// ---------------------------------------------------------------------------
// Kernel 1b: winner-takes-all -> compressed 12-input rows.
// lin[b][s][16] = {v4s, v5s, v5p, v6s, v6p, v7s, v7p, v8s+v8p,
//                  x0, x1, x2, x3, xsum, 0,0,0}
// 1024 blocks = (batch, quarter).
// ---------------------------------------------------------------------------
__global__ __launch_bounds__(256) void scatter_kernel(
    const float* __restrict__ x,
    const float* __restrict__ w4p, const float* __restrict__ w5p,
    const float* __restrict__ w6p, const float* __restrict__ w7p,
    const float* __restrict__ w8p,
    const float* __restrict__ MMg,
    float* __restrict__ lin)
{
    const int b    = blockIdx.x >> 2;
    const int quar = blockIdx.x & 3;
    const int tid  = threadIdx.x;
    const float* __restrict__ xr = x + (size_t)b * (4 * SEQ);

    float W4[4], W5[5], W6[6], W7[7], W8[8];
#pragma unroll
    for (int k = 0; k < 4; ++k) W4[k] = w4p[k];
#pragma unroll
    for (int k = 0; k < 5; ++k) W5[k] = w5p[k];
#pragma unroll
    for (int k = 0; k < 6; ++k) W6[k] = w6p[k];
#pragma unroll
    for (int k = 0; k < 7; ++k) W7[k] = w7p[k];
#pragma unroll
    for (int k = 0; k < 8; ++k) W8[k] = w8p[k];

    const float M4 = MMg[b * 5 + 0], M5 = MMg[b * 5 + 1], M6 = MMg[b * 5 + 2],
                M7 = MMg[b * 5 + 3], M8 = MMg[b * 5 + 4];

    for (int s = quar * (SEQ / 4) + tid; s < (quar + 1) * (SEQ / 4); s += 256) {
        float xw[12];
        if (s > 0) {
            const float4 t = *reinterpret_cast<const float4*>(xr + 4 * s - 4);
            xw[0] = t.x; xw[1] = t.y; xw[2] = t.z; xw[3] = t.w;
        } else { xw[0] = xw[1] = xw[2] = xw[3] = 0.f; }
        {
            const float4 t = *reinterpret_cast<const float4*>(xr + 4 * s);
            xw[4] = t.x; xw[5] = t.y; xw[6] = t.z; xw[7] = t.w;
        }
        if (s < SEQ - 1) {
            const float4 t = *reinterpret_cast<const float4*>(xr + 4 * s + 4);
            xw[8] = t.x; xw[9] = t.y; xw[10] = t.z; xw[11] = t.w;
        } else { xw[8] = xw[9] = xw[10] = xw[11] = 0.f; }

        float c4s = 0.f, c5s = 0.f, c6s = 0.f, c7s = 0.f, c8s = 0.f;
        float c5p = 0.f, c6p = 0.f, c7p = 0.f, c8p = 0.f;
#pragma unroll
        for (int t = 0; t < 4; ++t) c4s += xw[4 + t] * W4[t];
#pragma unroll
        for (int t = 0; t < 5; ++t) { c5s += xw[4 + t] * W5[t]; c5p += xw[t] * W5[t]; }
#pragma unroll
        for (int t = 0; t < 6; ++t) { c6s += xw[4 + t] * W6[t]; c6p += xw[t] * W6[t]; }
#pragma unroll
        for (int t = 0; t < 7; ++t) { c7s += xw[4 + t] * W7[t]; c7p += xw[t] * W7[t]; }
#pragma unroll
        for (int t = 0; t < 8; ++t) { c8s += xw[4 + t] * W8[t]; c8p += xw[t] * W8[t]; }

        const bool oks = (s < SEQ - 1);
        const bool okp = (s > 0);
        const float v4s = sqf(c4s + M4);
        const float v5s = oks ? sqf(c5s + M5) : 0.f;
        const float v6s = oks ? sqf(c6s + M6) : 0.f;
        const float v7s = oks ? sqf(c7s + M7) : 0.f;
        const float v8s = oks ? sqf(c8s + M8) : 0.f;
        const float v5p = okp ? sqf(c5p + M5) : 0.f;
        const float v6p = okp ? sqf(c6p + M6) : 0.f;
        const float v7p = okp ? sqf(c7p + M7) : 0.f;
        const float v8p = okp ? sqf(c8p + M8) : 0.f;

        const float xsum = (xw[4] + xw[5]) + (xw[6] + xw[7]);
        float4* op = reinterpret_cast<float4*>(lin + ((size_t)b * SEQ + s) * 16);
        op[0] = make_float4(v4s, v5s, v5p, v6s);
        op[1] = make_float4(v6p, v7s, v7p, v8s + v8p);
        op[2] = make_float4(xw[4], xw[5], xw[6], xw[7]);
        op[3] = make_float4(xsum, 0.f, 0.f, 0.f);
    }
}

// ---------------------------------------------------------------------------
// Kernel 2: segmented bidirectional LSTM, ONE fused wave per chain-segment.
// Grid = 2 segments x 512 chains = 1024 blocks x 64 thr = 1024 waves
// -> exactly 1 wave per SIMD (evidence r4 vs r6: co-located consumer chains
// serialize; per-SIMD consumer throughput is ~constant).
// Per 64-step chunk, the SAME wave:
//   1. moves the prefetched 16-float lin row (one step per lane) to locals,
//   2. issues next chunk's 4x global_load_dwordx4 (in flight ~18k cyc),
//   3. computes the 12-input x 40-row gate matvec (weights/bias/scales
//      pre-folded by wprep; wave-uniform s_load), writes LDS (stride 44),
//   4. s_waitcnt lgkmcnt(0) (same-wave DS ordering; no __syncthreads),
//   5. runs 64 recurrence steps (r4-proven critical-path algebra).
// Segment 1 warms up 128 steps from (h,c)=(0,0) (contraction; validated
// r5/r6: absmax 0.0), accS reset after warm chunks.
// ---------------------------------------------------------------------------
__global__ __launch_bounds__(64) void lstm_kernel(
    const float* __restrict__ lin,
    const float* __restrict__ Wp,
    const float* __restrict__ Whh_f,
    const float* __restrict__ Whh_r,
    float* __restrict__ P)
{
    const int seg  = blockIdx.x >> 9;        // 0..1
    const int cb   = blockIdx.x & 511;       // (d<<8) + b
    const int d    = cb >> 8;
    const int b    = cb & 255;
    const int lane = threadIdx.x;

    const int s0         = seg ? (2048 - 128) : 0;
    const int nChunks    = seg ? 34 : 32;    // 64-step chunks
    const int warmChunks = seg ? 2 : 0;

    __shared__ float gbuf[64 * 44];
    __shared__ float xbuf[64];

    // ---- consumer setup: lane = 4*unit + gate(i,f,g,o) ----
    const int j = lane >> 2;
    const int t = lane & 3;
    int row = t * 10 + j;
    if (lane >= 40) row = 0;

    const float* __restrict__ Whh = d ? Whh_r : Whh_f;
    const float mpre = (t == 2) ? (-2.f * L2E) : (-L2E);
    float whh[10];
#pragma unroll
    for (int k = 0; k < 10; ++k) whh[k] = Whh[row * 10 + k] * mpre;
    const float mpost = (t == 0) ? (-2.f * L2E) : ((t == 1) ? 1.f : 2.f);
    const float apost = (t == 2) ? -1.f : 0.f;

    const float* __restrict__ Wrow = Wp + d * 40 * 16;   // wave-uniform
    const float* __restrict__ base = lin + (size_t)b * SEQ * 16;

    auto rowptr = [&](int cn) {
        const int s   = s0 + cn * 64 + lane;
        const int pos = d ? (SEQ - 1 - s) : s;
        return reinterpret_cast<const float4*>(base + (size_t)pos * 16);
    };

    float4 p0, p1, p2, p3;
    { const float4* a = rowptr(0); p0 = a[0]; p1 = a[1]; p2 = a[2]; p3 = a[3]; }

    float cs = 0.f, h = 0.f, accS = 0.f;

    for (int cn = 0; cn < nChunks; ++cn) {
        // -- 1. move prefetched row to locals --
        const float in0 = p0.x, in1 = p0.y, in2 = p0.z, in3 = p0.w;
        const float in4 = p1.x, in5 = p1.y, in6 = p1.z, in7 = p1.w;
        const float x0 = p2.x, x1 = p2.y, x2 = p2.z, x3 = p2.w;
        const float xs = p3.x;
        // -- 2. prefetch next chunk --
        {
            const int nc = (cn + 1 < nChunks) ? cn + 1 : cn;
            const float4* a = rowptr(nc);
            p0 = a[0]; p1 = a[1]; p2 = a[2]; p3 = a[3];
        }
        // -- 3. producer matvec: 40 rows x 12 inputs (uniform weights) --
        xbuf[lane] = xs;
#pragma unroll
        for (int q = 0; q < 10; ++q) {
            float o4[4];
#pragma unroll
            for (int rr = 0; rr < 4; ++rr) {
                const float* __restrict__ w = Wrow + (q * 4 + rr) * 16;
                float a0 = w[12], a1 = 0.f, a2 = 0.f, a3 = 0.f;
                a0 = fmaf(in0, w[0], a0);  a1 = fmaf(in1, w[1], a1);
                a2 = fmaf(in2, w[2], a2);  a3 = fmaf(in3, w[3], a3);
                a0 = fmaf(in4, w[4], a0);  a1 = fmaf(in5, w[5], a1);
                a2 = fmaf(in6, w[6], a2);  a3 = fmaf(in7, w[7], a3);
                a0 = fmaf(x0,  w[8], a0);  a1 = fmaf(x1,  w[9], a1);
                a2 = fmaf(x2,  w[10], a2); a3 = fmaf(x3,  w[11], a3);
                o4[rr] = (a0 + a1) + (a2 + a3);
            }
            *reinterpret_cast<float4*>(&gbuf[lane * 44 + q * 4]) =
                make_float4(o4[0], o4[1], o4[2], o4[3]);
        }
        // -- 4. same-wave DS ordering (no barrier needed: single wave) --
        asm volatile("s_waitcnt lgkmcnt(0)" ::: "memory");
        // -- 5. consume 64 steps --
#pragma unroll 8
        for (int i = 0; i < 64; ++i) {
            const float g  = gbuf[i * 44 + row];
            const float sx = xbuf[i];
            const int hb = __float_as_int(h);
            float a0 = g, a1, a2, a3;
            a0 = fmaf(__int_as_float(__builtin_amdgcn_readlane(hb,  0)), whh[0], a0);
            a1 =      __int_as_float(__builtin_amdgcn_readlane(hb,  4)) * whh[1];
            a2 =      __int_as_float(__builtin_amdgcn_readlane(hb,  8)) * whh[2];
            a3 =      __int_as_float(__builtin_amdgcn_readlane(hb, 12)) * whh[3];
            a0 = fmaf(__int_as_float(__builtin_amdgcn_readlane(hb, 16)), whh[4], a0);
            a1 = fmaf(__int_as_float(__builtin_amdgcn_readlane(hb, 20)), whh[5], a1);
            a2 = fmaf(__int_as_float(__builtin_amdgcn_readlane(hb, 24)), whh[6], a2);
            a3 = fmaf(__int_as_float(__builtin_amdgcn_readlane(hb, 28)), whh[7], a3);
            a0 = fmaf(__int_as_float(__builtin_amdgcn_readlane(hb, 32)), whh[8], a0);
            a1 = fmaf(__int_as_float(__builtin_amdgcn_readlane(hb, 36)), whh[9], a1);
            const float e = (a0 + a2) + (a1 + a3);
            const float u1 = fexp2(e);
            const float rr = frcp(1.f + u1);
            const float a  = fmaf(rr, mpost, apost);
            const int ab = __float_as_int(a);
            const float iv  = __int_as_float(__builtin_amdgcn_update_dpp(ab, ab, 0x00, 0xF, 0xF, false));
            const float fv  = __int_as_float(__builtin_amdgcn_update_dpp(ab, ab, 0x55, 0xF, 0xF, false));
            const float gv  = __int_as_float(__builtin_amdgcn_update_dpp(ab, ab, 0xAA, 0xF, 0xF, false));
            const float ov2 = __int_as_float(__builtin_amdgcn_update_dpp(ab, ab, 0xFF, 0xF, 0xF, false));
            cs = fmaf(fv, cs, iv * gv);
            const float movh = -0.5f * ov2;
            const float u2 = fexp2(cs);
            const float r2 = frcp(1.f + u2);
            h = fmaf(ov2, r2, movh);
            accS = fmaf(sx, h, accS);
        }
        if (cn + 1 == warmChunks) accS = 0.f;   // drop warmup contributions
    }

    float v = (lane < 40) ? accS * 0.25f : 0.f;
#pragma unroll
    for (int off = 32; off; off >>= 1) v += __shfl_down(v, off);
    if (lane == 0) P[seg * 512 + cb] = v;
}

// ---------------------------------------------------------------------------
// Kernel 3: out[b] = sigmoid( sum over 2 segments x 2 directions )
// ---------------------------------------------------------------------------
__global__ __launch_bounds__(256) void final_kernel(const float* __restrict__ P,
                                                    float* __restrict__ out)
{
    const int b = threadIdx.x;
    float v = 0.f;
#pragma unroll
    for (int seg = 0; seg < 2; ++seg)
        v += P[seg * 512 + b] + P[seg * 512 + 256 + b];
    out[b] = frcp(1.f + fexp2(-v * L2E));
}

extern "C" void kernel_launch(void* const* d_in, const int* in_sizes, int n_in,
                              void* d_out, int out_size, void* d_ws, size_t ws_size,
                              hipStream_t stream)
{
    const float* x     = (const float*)d_in[0];
    const float* w4    = (const float*)d_in[1];
    const float* w5    = (const float*)d_in[2];
    const float* w6    = (const float*)d_in[3];
    const float* w7    = (const float*)d_in[4];
    const float* w8    = (const float*)d_in[5];
    const float* Wih_f = (const float*)d_in[6];
    const float* Whh_f = (const float*)d_in[7];
    const float* bih_f = (const float*)d_in[8];
    const float* bhh_f = (const float*)d_in[9];
    const float* Wih_r = (const float*)d_in[10];
    const float* Whh_r = (const float*)d_in[11];
    const float* bih_r = (const float*)d_in[12];
    const float* bhh_r = (const float*)d_in[13];

    // ws layout (fp32): lin [256][4096][16] (64MB) | P[1024] | MM[1280] | Wp[1280]
    float* lin = (float*)d_ws;
    float* P   = lin + (size_t)NBATCH * SEQ * 16;
    float* MM  = P + 1024;
    float* Wpp = MM + 1280;

    wprep_kernel<<<1, 128, 0, stream>>>(Wih_f, bih_f, bhh_f,
                                        Wih_r, bih_r, bhh_r, Wpp);
    max_kernel<<<NBATCH, 256, 0, stream>>>(x, w4, w5, w6, w7, w8, MM);
    scatter_kernel<<<4 * NBATCH, 256, 0, stream>>>(x, w4, w5, w6, w7, w8, MM, lin);
    lstm_kernel<<<2 * 2 * NBATCH, 64, 0, stream>>>(lin, Wpp, Whh_f, Whh_r, P);
    final_kernel<<<1, NBATCH, 0, stream>>>(P, (float*)d_out);
}

// Round 8
// 353.921 us; speedup vs baseline: 1.5296x; 1.5296x over previous
//
#include <hip/hip_runtime.h>

#define SEQ 4096
#define NBATCH 256

__device__ __forceinline__ float sqf(float v) { return v * v; }
__device__ __forceinline__ float fexp2(float v) { return __builtin_amdgcn_exp2f(v); }
__device__ __forceinline__ float frcp(float v)  { return __builtin_amdgcn_rcpf(v); }

#define L2E 1.4426950408889634f

// ---------------------------------------------------------------------------
// Kernel 0: fold the 24-wide input matvec into 12 inputs + bias, pre-scaled
// by the row's activation pre-scale (-log2e; -2log2e for g rows).
// Wp[d][r][16] = {w0..w11, bias, 0,0,0}
// ---------------------------------------------------------------------------
__global__ void wprep_kernel(
    const float* __restrict__ Wih_f, const float* __restrict__ bih_f,
    const float* __restrict__ bhh_f,
    const float* __restrict__ Wih_r, const float* __restrict__ bih_r,
    const float* __restrict__ bhh_r,
    float* __restrict__ Wp)
{
    const int t = threadIdx.x;
    if (t >= 80) return;
    const int d = t / 40, r = t % 40;
    const float* __restrict__ W  = (d ? Wih_r : Wih_f) + r * 24;
    const float* __restrict__ bi = d ? bih_r : bih_f;
    const float* __restrict__ bh = d ? bhh_r : bhh_f;
    const float sc = (r >= 20 && r < 30) ? (-2.f * L2E) : (-L2E);
    float o[13];
    o[0]  = W[0] + W[1] + W[2] + W[3];                // v4s
    o[1]  = W[4] + W[5] + W[6] + W[7];                // v5s
    o[2]  = W[4];                                     // v5p
    o[3]  = W[8] + W[9] + W[10] + W[11];              // v6s
    o[4]  = W[8] + W[9];                              // v6p
    o[5]  = W[12] + W[13] + W[14] + W[15];            // v7s
    o[6]  = W[12] + W[13] + W[14];                    // v7p
    o[7]  = W[16] + W[17] + W[18] + W[19];            // v8s+v8p
    o[8]  = W[20]; o[9] = W[21]; o[10] = W[22]; o[11] = W[23];   // x0..x3
    o[12] = bi[r] + bh[r];
    float* __restrict__ out = Wp + (d * 40 + r) * 16;
#pragma unroll
    for (int k = 0; k < 13; ++k) out[k] = o[k] * sc;
    out[13] = 0.f; out[14] = 0.f; out[15] = 0.f;
}

// ---------------------------------------------------------------------------
// Kernel 1a: per-batch conv max. One block per batch row; writes MM[b][5].
// ---------------------------------------------------------------------------
__global__ __launch_bounds__(256) void max_kernel(
    const float* __restrict__ x,
    const float* __restrict__ w4p, const float* __restrict__ w5p,
    const float* __restrict__ w6p, const float* __restrict__ w7p,
    const float* __restrict__ w8p,
    float* __restrict__ MMg)
{
    const int b   = blockIdx.x;
    const int tid = threadIdx.x;
    const float* __restrict__ xr = x + (size_t)b * (4 * SEQ);

    float W4[4], W5[5], W6[6], W7[7], W8[8];
#pragma unroll
    for (int k = 0; k < 4; ++k) W4[k] = w4p[k];
#pragma unroll
    for (int k = 0; k < 5; ++k) W5[k] = w5p[k];
#pragma unroll
    for (int k = 0; k < 6; ++k) W6[k] = w6p[k];
#pragma unroll
    for (int k = 0; k < 7; ++k) W7[k] = w7p[k];
#pragma unroll
    for (int k = 0; k < 8; ++k) W8[k] = w8p[k];

    float m4 = -3.4e38f, m5 = -3.4e38f, m6 = -3.4e38f, m7 = -3.4e38f, m8 = -3.4e38f;
    for (int i = tid; i < SEQ; i += 256) {
        const float4 t0 = *reinterpret_cast<const float4*>(xr + 4 * i);
        const float xa0 = t0.x, xa1 = t0.y, xa2 = t0.z, xa3 = t0.w;
        const float c4 = xa0 * W4[0] + xa1 * W4[1] + xa2 * W4[2] + xa3 * W4[3];
        m4 = fmaxf(m4, c4);
        if (i < SEQ - 1) {
            const float4 t1 = *reinterpret_cast<const float4*>(xr + 4 * i + 4);
            const float xa4 = t1.x, xa5 = t1.y, xa6 = t1.z, xa7 = t1.w;
            const float c5 = xa0*W5[0]+xa1*W5[1]+xa2*W5[2]+xa3*W5[3]+xa4*W5[4];
            const float c6 = xa0*W6[0]+xa1*W6[1]+xa2*W6[2]+xa3*W6[3]+xa4*W6[4]+xa5*W6[5];
            const float c7 = xa0*W7[0]+xa1*W7[1]+xa2*W7[2]+xa3*W7[3]+xa4*W7[4]+xa5*W7[5]+xa6*W7[6];
            const float c8 = xa0*W8[0]+xa1*W8[1]+xa2*W8[2]+xa3*W8[3]+xa4*W8[4]+xa5*W8[5]+xa6*W8[6]+xa7*W8[7];
            m5 = fmaxf(m5, c5); m6 = fmaxf(m6, c6);
            m7 = fmaxf(m7, c7); m8 = fmaxf(m8, c8);
        }
    }
#pragma unroll
    for (int off = 32; off; off >>= 1) {
        m4 = fmaxf(m4, __shfl_down(m4, off));
        m5 = fmaxf(m5, __shfl_down(m5, off));
        m6 = fmaxf(m6, __shfl_down(m6, off));
        m7 = fmaxf(m7, __shfl_down(m7, off));
        m8 = fmaxf(m8, __shfl_down(m8, off));
    }
    __shared__ float wr[4][5];
    if ((tid & 63) == 0) {
        const int w = tid >> 6;
        wr[w][0] = m4; wr[w][1] = m5; wr[w][2] = m6; wr[w][3] = m7; wr[w][4] = m8;
    }
    __syncthreads();
    if (tid < 5)
        MMg[b * 5 + tid] = fmaxf(fmaxf(wr[0][tid], wr[1][tid]),
                                 fmaxf(wr[2][tid], wr[3][tid]));
}

// ---------------------------------------------------------------------------
// Kernel 1b: winner-takes-all -> compressed 12-input rows.
// lin[b][s][16] = {v4s, v5s, v5p, v6s, v6p, v7s, v7p, v8s+v8p,
//                  x0, x1, x2, x3, xsum, 0,0,0}
// ---------------------------------------------------------------------------
__global__ __launch_bounds__(256) void scatter_kernel(
    const float* __restrict__ x,
    const float* __restrict__ w4p, const float* __restrict__ w5p,
    const float* __restrict__ w6p, const float* __restrict__ w7p,
    const float* __restrict__ w8p,
    const float* __restrict__ MMg,
    float* __restrict__ lin)
{
    const int b    = blockIdx.x >> 2;
    const int quar = blockIdx.x & 3;
    const int tid  = threadIdx.x;
    const float* __restrict__ xr = x + (size_t)b * (4 * SEQ);

    float W4[4], W5[5], W6[6], W7[7], W8[8];
#pragma unroll
    for (int k = 0; k < 4; ++k) W4[k] = w4p[k];
#pragma unroll
    for (int k = 0; k < 5; ++k) W5[k] = w5p[k];
#pragma unroll
    for (int k = 0; k < 6; ++k) W6[k] = w6p[k];
#pragma unroll
    for (int k = 0; k < 7; ++k) W7[k] = w7p[k];
#pragma unroll
    for (int k = 0; k < 8; ++k) W8[k] = w8p[k];

    const float M4 = MMg[b * 5 + 0], M5 = MMg[b * 5 + 1], M6 = MMg[b * 5 + 2],
                M7 = MMg[b * 5 + 3], M8 = MMg[b * 5 + 4];

    for (int s = quar * (SEQ / 4) + tid; s < (quar + 1) * (SEQ / 4); s += 256) {
        float xw[12];
        if (s > 0) {
            const float4 t = *reinterpret_cast<const float4*>(xr + 4 * s - 4);
            xw[0] = t.x; xw[1] = t.y; xw[2] = t.z; xw[3] = t.w;
        } else { xw[0] = xw[1] = xw[2] = xw[3] = 0.f; }
        {
            const float4 t = *reinterpret_cast<const float4*>(xr + 4 * s);
            xw[4] = t.x; xw[5] = t.y; xw[6] = t.z; xw[7] = t.w;
        }
        if (s < SEQ - 1) {
            const float4 t = *reinterpret_cast<const float4*>(xr + 4 * s + 4);
            xw[8] = t.x; xw[9] = t.y; xw[10] = t.z; xw[11] = t.w;
        } else { xw[8] = xw[9] = xw[10] = xw[11] = 0.f; }

        float c4s = 0.f, c5s = 0.f, c6s = 0.f, c7s = 0.f, c8s = 0.f;
        float c5p = 0.f, c6p = 0.f, c7p = 0.f, c8p = 0.f;
#pragma unroll
        for (int t = 0; t < 4; ++t) c4s += xw[4 + t] * W4[t];
#pragma unroll
        for (int t = 0; t < 5; ++t) { c5s += xw[4 + t] * W5[t]; c5p += xw[t] * W5[t]; }
#pragma unroll
        for (int t = 0; t < 6; ++t) { c6s += xw[4 + t] * W6[t]; c6p += xw[t] * W6[t]; }
#pragma unroll
        for (int t = 0; t < 7; ++t) { c7s += xw[4 + t] * W7[t]; c7p += xw[t] * W7[t]; }
#pragma unroll
        for (int t = 0; t < 8; ++t) { c8s += xw[4 + t] * W8[t]; c8p += xw[t] * W8[t]; }

        const bool oks = (s < SEQ - 1);
        const bool okp = (s > 0);
        const float v4s = sqf(c4s + M4);
        const float v5s = oks ? sqf(c5s + M5) : 0.f;
        const float v6s = oks ? sqf(c6s + M6) : 0.f;
        const float v7s = oks ? sqf(c7s + M7) : 0.f;
        const float v8s = oks ? sqf(c8s + M8) : 0.f;
        const float v5p = okp ? sqf(c5p + M5) : 0.f;
        const float v6p = okp ? sqf(c6p + M6) : 0.f;
        const float v7p = okp ? sqf(c7p + M7) : 0.f;
        const float v8p = okp ? sqf(c8p + M8) : 0.f;

        const float xsum = (xw[4] + xw[5]) + (xw[6] + xw[7]);
        float4* op = reinterpret_cast<float4*>(lin + ((size_t)b * SEQ + s) * 16);
        op[0] = make_float4(v4s, v5s, v5p, v6s);
        op[1] = make_float4(v6p, v7s, v7p, v8s + v8p);
        op[2] = make_float4(xw[4], xw[5], xw[6], xw[7]);
        op[3] = make_float4(xsum, 0.f, 0.f, 0.f);
    }
}

// ---------------------------------------------------------------------------
// Kernel 2: segmented bidirectional LSTM, 4 chains per wave, K=8 segments.
// Grid = 8 seg x 2 dir x 64 batch-groups = 1024 blocks x 64 thr = 1 wave/SIMD.
// Wave handles 4 chains (same seg+dir, batches b0..b0+3), 16-lane groups:
//   consumer lane = (chain c = lane>>4, unit j = lane&15, j<10 active).
//   ALL 4 GATES IN-LANE -> no DPP exchange; activation constants are
//   compile-time per gate. h-exchange via 10 ds_bpermute within the group.
// Producer (same wave, data-parallel): lane = (chain cc = lane&3,
//   step irow = lane>>2), handles steps irow and irow+16 of the 32-step
//   chunk; 12-input matvec with weights cached in LDS (loaded once ->
//   no per-chunk s_load stalls, r7's failure mode).
// gbuf[step][chain][unit][gate] (stride 44/step-chain) -> consumer reads its
// 4 gate preacts with ONE ds_read_b128.
// Segment k>0 warms up 128 steps from (h,c)=(0,0) (contraction; absmax 0.0
// validated r5/r6); accS reset after warm chunks.
// ---------------------------------------------------------------------------
__global__ __launch_bounds__(64) void lstm_kernel(
    const float* __restrict__ lin,
    const float* __restrict__ Wp,
    const float* __restrict__ Whh_f,
    const float* __restrict__ Whh_r,
    float* __restrict__ P)
{
    const int bg   = blockIdx.x & 63;
    const int dseg = blockIdx.x >> 6;     // 0..15
    const int d    = dseg & 1;
    const int seg  = dseg >> 1;           // 0..7
    const int b0   = bg * 4;
    const int lane = threadIdx.x;

    const int s0         = seg * 512 - (seg ? 128 : 0);
    const int nChunks    = seg ? 20 : 16;    // 32-step chunks
    const int warmChunks = seg ? 4 : 0;

    __shared__ float gbuf[32 * 4 * 44];      // [step][chain] stride 44
    __shared__ float xbuf[32 * 4];           // [step][chain]
    __shared__ float wbuf[40 * 16];          // folded input weights, this dir

    // ---- load folded weights into LDS once ----
    {
        const float* __restrict__ src = Wp + d * 640;
#pragma unroll
        for (int q = 0; q < 10; ++q) wbuf[lane + 64 * q] = src[lane + 64 * q];
    }
    asm volatile("s_waitcnt lgkmcnt(0)" ::: "memory");

    // ---- consumer setup: c = lane>>4, unit j = lane&15 (clamped) ----
    const int c  = lane >> 4;
    const int jr = lane & 15;
    const int jc = (jr < 10) ? jr : 0;
    const int gb4 = (lane & 48) * 4;         // group base, byte index for bpermute

    const float* __restrict__ Whh = d ? Whh_r : Whh_f;
    float wI[10], wF[10], wG[10], wO[10];
#pragma unroll
    for (int k = 0; k < 10; ++k) {
        wI[k] = Whh[(0 * 10 + jc) * 10 + k] * (-L2E);
        wF[k] = Whh[(1 * 10 + jc) * 10 + k] * (-L2E);
        wG[k] = Whh[(2 * 10 + jc) * 10 + k] * (-2.f * L2E);
        wO[k] = Whh[(3 * 10 + jc) * 10 + k] * (-L2E);
    }

    // ---- producer setup ----
    const int cc   = lane & 3;
    const int irow = lane >> 2;              // 0..15
    const float* __restrict__ chbase = lin + (size_t)(b0 + cc) * SEQ * 16;

    auto rowp = [&](int cn, int i) {
        const int sp  = s0 + cn * 32 + i;
        const int pos = d ? (SEQ - 1 - sp) : sp;
        return reinterpret_cast<const float4*>(chbase + (size_t)pos * 16);
    };

    float4 pA0, pA1, pA2, pA3, pB0, pB1, pB2, pB3;
    {
        const float4* a = rowp(0, irow);
        pA0 = a[0]; pA1 = a[1]; pA2 = a[2]; pA3 = a[3];
        const float4* bp = rowp(0, irow + 16);
        pB0 = bp[0]; pB1 = bp[1]; pB2 = bp[2]; pB3 = bp[3];
    }

    float cs = 0.f, h = 0.f, accS = 0.f;

    for (int cn = 0; cn < nChunks; ++cn) {
        // ---- producer: matvec for steps irow, irow+16 of this chunk ----
        {
            const float vA[12] = {pA0.x, pA0.y, pA0.z, pA0.w,
                                  pA1.x, pA1.y, pA1.z, pA1.w,
                                  pA2.x, pA2.y, pA2.z, pA2.w};
            const float vB[12] = {pB0.x, pB0.y, pB0.z, pB0.w,
                                  pB1.x, pB1.y, pB1.z, pB1.w,
                                  pB2.x, pB2.y, pB2.z, pB2.w};
            xbuf[irow * 4 + cc]        = pA3.x;
            xbuf[(irow + 16) * 4 + cc] = pB3.x;
            const int baseA = (irow * 4 + cc) * 44;
            const int baseB = ((irow + 16) * 4 + cc) * 44;
#pragma unroll
            for (int j = 0; j < 10; ++j) {
                float oA[4], oB[4];
#pragma unroll
                for (int g = 0; g < 4; ++g) {
                    const int r = g * 10 + j;
                    const float4 w0 = *reinterpret_cast<const float4*>(&wbuf[r * 16 + 0]);
                    const float4 w1 = *reinterpret_cast<const float4*>(&wbuf[r * 16 + 4]);
                    const float4 w2 = *reinterpret_cast<const float4*>(&wbuf[r * 16 + 8]);
                    const float4 w3 = *reinterpret_cast<const float4*>(&wbuf[r * 16 + 12]);
                    float a0 = w3.x, a1 = 0.f, a2 = 0.f, a3 = 0.f;
                    a0 = fmaf(vA[0], w0.x, a0); a1 = fmaf(vA[1], w0.y, a1);
                    a2 = fmaf(vA[2], w0.z, a2); a3 = fmaf(vA[3], w0.w, a3);
                    a0 = fmaf(vA[4], w1.x, a0); a1 = fmaf(vA[5], w1.y, a1);
                    a2 = fmaf(vA[6], w1.z, a2); a3 = fmaf(vA[7], w1.w, a3);
                    a0 = fmaf(vA[8], w2.x, a0); a1 = fmaf(vA[9], w2.y, a1);
                    a2 = fmaf(vA[10], w2.z, a2); a3 = fmaf(vA[11], w2.w, a3);
                    oA[g] = (a0 + a1) + (a2 + a3);
                    float b0_ = w3.x, b1_ = 0.f, b2_ = 0.f, b3_ = 0.f;
                    b0_ = fmaf(vB[0], w0.x, b0_); b1_ = fmaf(vB[1], w0.y, b1_);
                    b2_ = fmaf(vB[2], w0.z, b2_); b3_ = fmaf(vB[3], w0.w, b3_);
                    b0_ = fmaf(vB[4], w1.x, b0_); b1_ = fmaf(vB[5], w1.y, b1_);
                    b2_ = fmaf(vB[6], w1.z, b2_); b3_ = fmaf(vB[7], w1.w, b3_);
                    b0_ = fmaf(vB[8], w2.x, b0_); b1_ = fmaf(vB[9], w2.y, b1_);
                    b2_ = fmaf(vB[10], w2.z, b2_); b3_ = fmaf(vB[11], w2.w, b3_);
                    oB[g] = (b0_ + b1_) + (b2_ + b3_);
                }
                *reinterpret_cast<float4*>(&gbuf[baseA + j * 4]) =
                    make_float4(oA[0], oA[1], oA[2], oA[3]);
                *reinterpret_cast<float4*>(&gbuf[baseB + j * 4]) =
                    make_float4(oB[0], oB[1], oB[2], oB[3]);
            }
        }
        // ---- prefetch next chunk's rows (overlaps the consume phase) ----
        {
            const int nc = (cn + 1 < nChunks) ? cn + 1 : cn;
            const float4* a = rowp(nc, irow);
            pA0 = a[0]; pA1 = a[1]; pA2 = a[2]; pA3 = a[3];
            const float4* bp = rowp(nc, irow + 16);
            pB0 = bp[0]; pB1 = bp[1]; pB2 = bp[2]; pB3 = bp[3];
        }
        // ---- same-wave DS ordering (single wave: no barrier) ----
        asm volatile("s_waitcnt lgkmcnt(0)" ::: "memory");
        // ---- consume 32 steps ----
#pragma unroll 8
        for (int i = 0; i < 32; ++i) {
            const float4 gp4 =
                *reinterpret_cast<const float4*>(&gbuf[(i * 4 + c) * 44 + jc * 4]);
            const float sx = xbuf[i * 4 + c];
            const int hb = __float_as_int(h);
            float hj[10];
#pragma unroll
            for (int k = 0; k < 10; ++k)
                hj[k] = __int_as_float(
                    __builtin_amdgcn_ds_bpermute(gb4 + 4 * k, hb));
            float i0 = gp4.x, i1 = 0.f, f0 = gp4.y, f1 = 0.f;
            float g0 = gp4.z, g1 = 0.f, o0 = gp4.w, o1 = 0.f;
#pragma unroll
            for (int k = 0; k < 10; k += 2) {
                i0 = fmaf(hj[k], wI[k], i0); i1 = fmaf(hj[k + 1], wI[k + 1], i1);
                f0 = fmaf(hj[k], wF[k], f0); f1 = fmaf(hj[k + 1], wF[k + 1], f1);
                g0 = fmaf(hj[k], wG[k], g0); g1 = fmaf(hj[k + 1], wG[k + 1], g1);
                o0 = fmaf(hj[k], wO[k], o0); o1 = fmaf(hj[k + 1], wO[k + 1], o1);
            }
            const float ei = i0 + i1, ef = f0 + f1, eg = g0 + g1, eo = o0 + o1;
            const float si2 = frcp(1.f + fexp2(ei)) * (-2.f * L2E); // -2L2E*sigma_i
            const float sf  = frcp(1.f + fexp2(ef));                // sigma_f
            const float tg  = fmaf(frcp(1.f + fexp2(eg)), 2.f, -1.f); // tanh
            const float so2 = frcp(1.f + fexp2(eo)) * 2.f;          // 2*sigma_o
            cs = fmaf(sf, cs, si2 * tg);                 // cs = -2L2E * c
            const float rc = frcp(1.f + fexp2(cs));
            h = (rc - 0.5f) * so2;                       // o * tanh(c)
            accS = fmaf(sx, h, accS);
        }
        if (cn + 1 == warmChunks) accS = 0.f;   // drop warmup contributions
    }

    // ---- group reduction: sum accS over units 0..9 of each 16-lane group ----
    float v = (jr < 10) ? accS : 0.f;
#pragma unroll
    for (int off = 1; off <= 8; off <<= 1) v += __shfl_down(v, off);
    if (jr == 0) P[seg * 512 + d * 256 + b0 + c] = v;
}

// ---------------------------------------------------------------------------
// Kernel 3: out[b] = sigmoid( sum over 8 segments x 2 directions )
// ---------------------------------------------------------------------------
__global__ __launch_bounds__(256) void final_kernel(const float* __restrict__ P,
                                                    float* __restrict__ out)
{
    const int b = threadIdx.x;
    float v = 0.f;
#pragma unroll
    for (int seg = 0; seg < 8; ++seg)
        v += P[seg * 512 + b] + P[seg * 512 + 256 + b];
    out[b] = frcp(1.f + fexp2(-v * L2E));
}

extern "C" void kernel_launch(void* const* d_in, const int* in_sizes, int n_in,
                              void* d_out, int out_size, void* d_ws, size_t ws_size,
                              hipStream_t stream)
{
    const float* x     = (const float*)d_in[0];
    const float* w4    = (const float*)d_in[1];
    const float* w5    = (const float*)d_in[2];
    const float* w6    = (const float*)d_in[3];
    const float* w7    = (const float*)d_in[4];
    const float* w8    = (const float*)d_in[5];
    const float* Wih_f = (const float*)d_in[6];
    const float* Whh_f = (const float*)d_in[7];
    const float* bih_f = (const float*)d_in[8];
    const float* bhh_f = (const float*)d_in[9];
    const float* Wih_r = (const float*)d_in[10];
    const float* Whh_r = (const float*)d_in[11];
    const float* bih_r = (const float*)d_in[12];
    const float* bhh_r = (const float*)d_in[13];

    // ws layout (fp32): lin [256][4096][16] (64MB) | P[4096] | MM[1280] | Wp[1280]
    float* lin = (float*)d_ws;
    float* P   = lin + (size_t)NBATCH * SEQ * 16;
    float* MM  = P + 4096;
    float* Wpp = MM + 1280;

    wprep_kernel<<<1, 128, 0, stream>>>(Wih_f, bih_f, bhh_f,
                                        Wih_r, bih_r, bhh_r, Wpp);
    max_kernel<<<NBATCH, 256, 0, stream>>>(x, w4, w5, w6, w7, w8, MM);
    scatter_kernel<<<4 * NBATCH, 256, 0, stream>>>(x, w4, w5, w6, w7, w8, MM, lin);
    lstm_kernel<<<1024, 64, 0, stream>>>(lin, Wpp, Whh_f, Whh_r, P);
    final_kernel<<<1, NBATCH, 0, stream>>>(P, (float*)d_out);
}

// Round 9
// 331.198 us; speedup vs baseline: 1.6346x; 1.0686x over previous
//
#include <hip/hip_runtime.h>

#define SEQ 4096
#define NBATCH 256

typedef float v2f __attribute__((ext_vector_type(2)));

__device__ __forceinline__ float sqf(float v) { return v * v; }
__device__ __forceinline__ float fexp2(float v) { return __builtin_amdgcn_exp2f(v); }
__device__ __forceinline__ float frcp(float v)  { return __builtin_amdgcn_rcpf(v); }

#define L2E 1.4426950408889634f

// order-preserving float<->uint key for atomicMax on floats
__device__ __forceinline__ unsigned fkey(float f) {
    const int b = __float_as_int(f);
    return (unsigned)(b ^ ((b >> 31) | 0x80000000));
}
__device__ __forceinline__ float fival(unsigned k) {
    const int b = (k & 0x80000000u) ? (int)(k ^ 0x80000000u) : (int)(~k);
    return __int_as_float(b);
}

// ---------------------------------------------------------------------------
// Kernel 0: fold the 24-wide input matvec into 12 inputs + bias, pre-scaled
// by the row's activation pre-scale (-log2e; -2log2e for g rows).
// Also zero-initializes the MMu atomic-max buffer (re-poisoned every call).
// ---------------------------------------------------------------------------
__global__ void wprep_kernel(
    const float* __restrict__ Wih_f, const float* __restrict__ bih_f,
    const float* __restrict__ bhh_f,
    const float* __restrict__ Wih_r, const float* __restrict__ bih_r,
    const float* __restrict__ bhh_r,
    float* __restrict__ Wp, unsigned* __restrict__ MMu)
{
    const int t = threadIdx.x;
    for (int i = t; i < NBATCH * 5; i += 256) MMu[i] = 0u;  // key 0 < any real
    if (t >= 80) return;
    const int d = t / 40, r = t % 40;
    const float* __restrict__ W  = (d ? Wih_r : Wih_f) + r * 24;
    const float* __restrict__ bi = d ? bih_r : bih_f;
    const float* __restrict__ bh = d ? bhh_r : bhh_f;
    const float sc = (r >= 20 && r < 30) ? (-2.f * L2E) : (-L2E);
    float o[13];
    o[0]  = W[0] + W[1] + W[2] + W[3];                // v4s
    o[1]  = W[4] + W[5] + W[6] + W[7];                // v5s
    o[2]  = W[4];                                     // v5p
    o[3]  = W[8] + W[9] + W[10] + W[11];              // v6s
    o[4]  = W[8] + W[9];                              // v6p
    o[5]  = W[12] + W[13] + W[14] + W[15];            // v7s
    o[6]  = W[12] + W[13] + W[14];                    // v7p
    o[7]  = W[16] + W[17] + W[18] + W[19];            // v8s+v8p
    o[8]  = W[20]; o[9] = W[21]; o[10] = W[22]; o[11] = W[23];   // x0..x3
    o[12] = bi[r] + bh[r];
    float* __restrict__ out = Wp + (d * 40 + r) * 16;
#pragma unroll
    for (int k = 0; k < 13; ++k) out[k] = o[k] * sc;
    out[13] = 0.f; out[14] = 0.f; out[15] = 0.f;
}

// ---------------------------------------------------------------------------
// Kernel 1a: per-batch conv max -> atomicMax on uint keys.
// 1024 blocks = (batch, quarter) so the read is no longer latency-bound.
// ---------------------------------------------------------------------------
__global__ __launch_bounds__(256) void max_kernel(
    const float* __restrict__ x,
    const float* __restrict__ w4p, const float* __restrict__ w5p,
    const float* __restrict__ w6p, const float* __restrict__ w7p,
    const float* __restrict__ w8p,
    unsigned* __restrict__ MMu)
{
    const int b    = blockIdx.x >> 2;
    const int quar = blockIdx.x & 3;
    const int tid  = threadIdx.x;
    const float* __restrict__ xr = x + (size_t)b * (4 * SEQ);

    float W4[4], W5[5], W6[6], W7[7], W8[8];
#pragma unroll
    for (int k = 0; k < 4; ++k) W4[k] = w4p[k];
#pragma unroll
    for (int k = 0; k < 5; ++k) W5[k] = w5p[k];
#pragma unroll
    for (int k = 0; k < 6; ++k) W6[k] = w6p[k];
#pragma unroll
    for (int k = 0; k < 7; ++k) W7[k] = w7p[k];
#pragma unroll
    for (int k = 0; k < 8; ++k) W8[k] = w8p[k];

    float m4 = -3.4e38f, m5 = -3.4e38f, m6 = -3.4e38f, m7 = -3.4e38f, m8 = -3.4e38f;
    for (int i = quar * (SEQ / 4) + tid; i < (quar + 1) * (SEQ / 4); i += 256) {
        const float4 t0 = *reinterpret_cast<const float4*>(xr + 4 * i);
        const float xa0 = t0.x, xa1 = t0.y, xa2 = t0.z, xa3 = t0.w;
        const float c4 = xa0 * W4[0] + xa1 * W4[1] + xa2 * W4[2] + xa3 * W4[3];
        m4 = fmaxf(m4, c4);
        if (i < SEQ - 1) {
            const float4 t1 = *reinterpret_cast<const float4*>(xr + 4 * i + 4);
            const float xa4 = t1.x, xa5 = t1.y, xa6 = t1.z, xa7 = t1.w;
            const float c5 = xa0*W5[0]+xa1*W5[1]+xa2*W5[2]+xa3*W5[3]+xa4*W5[4];
            const float c6 = xa0*W6[0]+xa1*W6[1]+xa2*W6[2]+xa3*W6[3]+xa4*W6[4]+xa5*W6[5];
            const float c7 = xa0*W7[0]+xa1*W7[1]+xa2*W7[2]+xa3*W7[3]+xa4*W7[4]+xa5*W7[5]+xa6*W7[6];
            const float c8 = xa0*W8[0]+xa1*W8[1]+xa2*W8[2]+xa3*W8[3]+xa4*W8[4]+xa5*W8[5]+xa6*W8[6]+xa7*W8[7];
            m5 = fmaxf(m5, c5); m6 = fmaxf(m6, c6);
            m7 = fmaxf(m7, c7); m8 = fmaxf(m8, c8);
        }
    }
#pragma unroll
    for (int off = 32; off; off >>= 1) {
        m4 = fmaxf(m4, __shfl_down(m4, off));
        m5 = fmaxf(m5, __shfl_down(m5, off));
        m6 = fmaxf(m6, __shfl_down(m6, off));
        m7 = fmaxf(m7, __shfl_down(m7, off));
        m8 = fmaxf(m8, __shfl_down(m8, off));
    }
    __shared__ float wr[4][5];
    if ((tid & 63) == 0) {
        const int w = tid >> 6;
        wr[w][0] = m4; wr[w][1] = m5; wr[w][2] = m6; wr[w][3] = m7; wr[w][4] = m8;
    }
    __syncthreads();
    if (tid < 5) {
        const float m = fmaxf(fmaxf(wr[0][tid], wr[1][tid]),
                              fmaxf(wr[2][tid], wr[3][tid]));
        atomicMax(&MMu[b * 5 + tid], fkey(m));
    }
}

// ---------------------------------------------------------------------------
// Kernel 1b: winner-takes-all -> compressed 12-input rows.
// lin[b][s][16] = {v4s, v5s, v5p, v6s, v6p, v7s, v7p, v8s+v8p,
//                  x0, x1, x2, x3, xsum, 0,0,0}
// ---------------------------------------------------------------------------
__global__ __launch_bounds__(256) void scatter_kernel(
    const float* __restrict__ x,
    const float* __restrict__ w4p, const float* __restrict__ w5p,
    const float* __restrict__ w6p, const float* __restrict__ w7p,
    const float* __restrict__ w8p,
    const unsigned* __restrict__ MMu,
    float* __restrict__ lin)
{
    const int b    = blockIdx.x >> 2;
    const int quar = blockIdx.x & 3;
    const int tid  = threadIdx.x;
    const float* __restrict__ xr = x + (size_t)b * (4 * SEQ);

    float W4[4], W5[5], W6[6], W7[7], W8[8];
#pragma unroll
    for (int k = 0; k < 4; ++k) W4[k] = w4p[k];
#pragma unroll
    for (int k = 0; k < 5; ++k) W5[k] = w5p[k];
#pragma unroll
    for (int k = 0; k < 6; ++k) W6[k] = w6p[k];
#pragma unroll
    for (int k = 0; k < 7; ++k) W7[k] = w7p[k];
#pragma unroll
    for (int k = 0; k < 8; ++k) W8[k] = w8p[k];

    const float M4 = fival(MMu[b * 5 + 0]), M5 = fival(MMu[b * 5 + 1]),
                M6 = fival(MMu[b * 5 + 2]), M7 = fival(MMu[b * 5 + 3]),
                M8 = fival(MMu[b * 5 + 4]);

    for (int s = quar * (SEQ / 4) + tid; s < (quar + 1) * (SEQ / 4); s += 256) {
        float xw[12];
        if (s > 0) {
            const float4 t = *reinterpret_cast<const float4*>(xr + 4 * s - 4);
            xw[0] = t.x; xw[1] = t.y; xw[2] = t.z; xw[3] = t.w;
        } else { xw[0] = xw[1] = xw[2] = xw[3] = 0.f; }
        {
            const float4 t = *reinterpret_cast<const float4*>(xr + 4 * s);
            xw[4] = t.x; xw[5] = t.y; xw[6] = t.z; xw[7] = t.w;
        }
        if (s < SEQ - 1) {
            const float4 t = *reinterpret_cast<const float4*>(xr + 4 * s + 4);
            xw[8] = t.x; xw[9] = t.y; xw[10] = t.z; xw[11] = t.w;
        } else { xw[8] = xw[9] = xw[10] = xw[11] = 0.f; }

        float c4s = 0.f, c5s = 0.f, c6s = 0.f, c7s = 0.f, c8s = 0.f;
        float c5p = 0.f, c6p = 0.f, c7p = 0.f, c8p = 0.f;
#pragma unroll
        for (int t = 0; t < 4; ++t) c4s += xw[4 + t] * W4[t];
#pragma unroll
        for (int t = 0; t < 5; ++t) { c5s += xw[4 + t] * W5[t]; c5p += xw[t] * W5[t]; }
#pragma unroll
        for (int t = 0; t < 6; ++t) { c6s += xw[4 + t] * W6[t]; c6p += xw[t] * W6[t]; }
#pragma unroll
        for (int t = 0; t < 7; ++t) { c7s += xw[4 + t] * W7[t]; c7p += xw[t] * W7[t]; }
#pragma unroll
        for (int t = 0; t < 8; ++t) { c8s += xw[4 + t] * W8[t]; c8p += xw[t] * W8[t]; }

        const bool oks = (s < SEQ - 1);
        const bool okp = (s > 0);
        const float v4s = sqf(c4s + M4);
        const float v5s = oks ? sqf(c5s + M5) : 0.f;
        const float v6s = oks ? sqf(c6s + M6) : 0.f;
        const float v7s = oks ? sqf(c7s + M7) : 0.f;
        const float v8s = oks ? sqf(c8s + M8) : 0.f;
        const float v5p = okp ? sqf(c5p + M5) : 0.f;
        const float v6p = okp ? sqf(c6p + M6) : 0.f;
        const float v7p = okp ? sqf(c7p + M7) : 0.f;
        const float v8p = okp ? sqf(c8p + M8) : 0.f;

        const float xsum = (xw[4] + xw[5]) + (xw[6] + xw[7]);
        float4* op = reinterpret_cast<float4*>(lin + ((size_t)b * SEQ + s) * 16);
        op[0] = make_float4(v4s, v5s, v5p, v6s);
        op[1] = make_float4(v6p, v7s, v7p, v8s + v8p);
        op[2] = make_float4(xw[4], xw[5], xw[6], xw[7]);
        op[3] = make_float4(xsum, 0.f, 0.f, 0.f);
    }
}

// ---------------------------------------------------------------------------
// Kernel 2: K=16 segmented bidirectional LSTM, 4 spatial chains x 2 TEMPORAL
// segments per wave. Grid = 8 qpairs x 2 dir x 64 bgroups = 1024 blocks x
// 64 thr = 1 wave/SIMD. Temporal chains A (seg 2q) and B (seg 2q+1) are
// interleaved step-by-step so their dependence chains hide each other's
// bpermute/transcendental latency (r8: 60% of cycles were stall).
// All segments (incl. seg0) run 128 warm + 256 owned steps; seg0 resets
// (h,c)=0 after the warm chunks so its state at step 0 is exact. Warmup
// contraction validated r5/r6/r8 (absmax 0.0).
// Chunk = 16 steps: producer (same wave, lane = (chain, step)) fills both
// segments' gate buffers; matvecs packed as v2f -> v_pk_fma_f32.
// ---------------------------------------------------------------------------
__global__ __launch_bounds__(64) void lstm_kernel(
    const float* __restrict__ lin,
    const float* __restrict__ Wp,
    const float* __restrict__ Whh_f,
    const float* __restrict__ Whh_r,
    float* __restrict__ P)
{
    const int bg   = blockIdx.x & 63;
    const int d    = (blockIdx.x >> 6) & 1;
    const int q    = blockIdx.x >> 7;          // 0..7
    const int b0   = bg * 4;
    const int lane = threadIdx.x;

    const int segA = 2 * q, segB = 2 * q + 1;
    const int s0A = segA * 256 - 128;          // may be negative for q=0
    const int s0B = segB * 256 - 128;
    const int nChunks = 24, warmChunks = 8;    // 16-step chunks, 384 steps

    __shared__ float gbufA[16 * 4 * 44];
    __shared__ float gbufB[16 * 4 * 44];
    __shared__ float xbufA[64];
    __shared__ float xbufB[64];
    __shared__ float wbuf[640];                // folded input weights, this dir

    {
        const float* __restrict__ src = Wp + d * 640;
#pragma unroll
        for (int qq = 0; qq < 10; ++qq) wbuf[lane + 64 * qq] = src[lane + 64 * qq];
    }
    asm volatile("s_waitcnt lgkmcnt(0)" ::: "memory");

    // ---- consumer setup: c = lane>>4 (chain), jr = lane&15 (unit) ----
    const int c   = lane >> 4;
    const int jr  = lane & 15;
    const int jc  = (jr < 10) ? jr : 0;
    const int gb4 = (lane & 48) << 2;          // group base byte idx for bpermute

    const float* __restrict__ Whh = d ? Whh_r : Whh_f;
    v2f wIF[10], wGO[10];
#pragma unroll
    for (int k = 0; k < 10; ++k) {
        wIF[k] = (v2f){Whh[jc * 10 + k]        * (-L2E),
                       Whh[(10 + jc) * 10 + k] * (-L2E)};
        wGO[k] = (v2f){Whh[(20 + jc) * 10 + k] * (-2.f * L2E),
                       Whh[(30 + jc) * 10 + k] * (-L2E)};
    }

    // ---- producer setup: cc = lane&3 (chain), r = lane>>2 (step) ----
    const int cc = lane & 3;
    const int r  = lane >> 2;                  // 0..15
    const float* __restrict__ chbase = lin + (size_t)(b0 + cc) * SEQ * 16;

    auto rowp = [&](int s0, int cn) {
        int sp = s0 + cn * 16 + r;
        if (sp < 0) sp = 0;                    // q=0 warm region: clamped garbage,
                                               // discarded by the state reset
        const int pos = d ? (SEQ - 1 - sp) : sp;
        return reinterpret_cast<const float4*>(chbase + (size_t)pos * 16);
    };

    float4 pA[4], pB[4];
    {
        const float4* a = rowp(s0A, 0);
        pA[0] = a[0]; pA[1] = a[1]; pA[2] = a[2]; pA[3] = a[3];
        const float4* bq = rowp(s0B, 0);
        pB[0] = bq[0]; pB[1] = bq[1]; pB[2] = bq[2]; pB[3] = bq[3];
    }

    float csA = 0.f, hA = 0.f, accSA = 0.f;
    float csB = 0.f, hB = 0.f, accSB = 0.f;

    // one recurrence step (consumer)
    auto step = [&](const float* gb, const float* xb, float& cs, float& h,
                    float& accS, int i) {
        const float4 gp4 =
            *reinterpret_cast<const float4*>(&gb[(i * 4 + c) * 44 + jc * 4]);
        const float sx = xb[i * 4 + c];
        const int hb = __float_as_int(h);
        float hj[10];
#pragma unroll
        for (int k = 0; k < 10; ++k)
            hj[k] = __int_as_float(__builtin_amdgcn_ds_bpermute(gb4 + 4 * k, hb));
        v2f eif0 = (v2f){gp4.x, gp4.y}, eif1 = (v2f){0.f, 0.f};
        v2f ego0 = (v2f){gp4.z, gp4.w}, ego1 = (v2f){0.f, 0.f};
#pragma unroll
        for (int k = 0; k < 10; k += 2) {
            const v2f h0 = (v2f){hj[k], hj[k]};
            const v2f h1 = (v2f){hj[k + 1], hj[k + 1]};
            eif0 += h0 * wIF[k]; eif1 += h1 * wIF[k + 1];
            ego0 += h0 * wGO[k]; ego1 += h1 * wGO[k + 1];
        }
        const v2f eif = eif0 + eif1, ego = ego0 + ego1;
        const float si2 = frcp(1.f + fexp2(eif.x)) * (-2.f * L2E);
        const float sf  = frcp(1.f + fexp2(eif.y));
        const float tg  = fmaf(frcp(1.f + fexp2(ego.x)), 2.f, -1.f);
        const float so2 = frcp(1.f + fexp2(ego.y)) * 2.f;
        cs = fmaf(sf, cs, si2 * tg);               // cs = -2log2e * c
        h = (frcp(1.f + fexp2(cs)) - 0.5f) * so2;  // o * tanh(c)
        accS = fmaf(sx, h, accS);
    };

    for (int cn = 0; cn < nChunks; ++cn) {
        // ---- move prefetched rows to locals, issue next chunk's loads ----
        const float4 cA0 = pA[0], cA1 = pA[1], cA2 = pA[2], cA3 = pA[3];
        const float4 cB0 = pB[0], cB1 = pB[1], cB2 = pB[2], cB3 = pB[3];
        {
            const int nc = (cn + 1 < nChunks) ? cn + 1 : cn;
            const float4* a = rowp(s0A, nc);
            pA[0] = a[0]; pA[1] = a[1]; pA[2] = a[2]; pA[3] = a[3];
            const float4* bq = rowp(s0B, nc);
            pB[0] = bq[0]; pB[1] = bq[1]; pB[2] = bq[2]; pB[3] = bq[3];
        }
        // ---- producer: A/B packed matvec, 40 rows (pk_fma) ----
        xbufA[r * 4 + cc] = cA3.x;
        xbufB[r * 4 + cc] = cB3.x;
        v2f vab[12];
        vab[0]  = (v2f){cA0.x, cB0.x}; vab[1]  = (v2f){cA0.y, cB0.y};
        vab[2]  = (v2f){cA0.z, cB0.z}; vab[3]  = (v2f){cA0.w, cB0.w};
        vab[4]  = (v2f){cA1.x, cB1.x}; vab[5]  = (v2f){cA1.y, cB1.y};
        vab[6]  = (v2f){cA1.z, cB1.z}; vab[7]  = (v2f){cA1.w, cB1.w};
        vab[8]  = (v2f){cA2.x, cB2.x}; vab[9]  = (v2f){cA2.y, cB2.y};
        vab[10] = (v2f){cA2.z, cB2.z}; vab[11] = (v2f){cA2.w, cB2.w};
        const int wb = (r * 4 + cc) * 44;
#pragma unroll 2
        for (int j = 0; j < 10; ++j) {
            float oA[4], oB[4];
#pragma unroll
            for (int g = 0; g < 4; ++g) {
                const int rr = g * 10 + j;
                const float4 w0 = *reinterpret_cast<const float4*>(&wbuf[rr * 16 + 0]);
                const float4 w1 = *reinterpret_cast<const float4*>(&wbuf[rr * 16 + 4]);
                const float4 w2 = *reinterpret_cast<const float4*>(&wbuf[rr * 16 + 8]);
                const float  bb = wbuf[rr * 16 + 12];
                v2f a0 = (v2f){bb, bb}, a1 = (v2f){0.f, 0.f};
                v2f a2 = (v2f){0.f, 0.f}, a3 = (v2f){0.f, 0.f};
                a0 += vab[0]  * (v2f){w0.x, w0.x}; a1 += vab[1]  * (v2f){w0.y, w0.y};
                a2 += vab[2]  * (v2f){w0.z, w0.z}; a3 += vab[3]  * (v2f){w0.w, w0.w};
                a0 += vab[4]  * (v2f){w1.x, w1.x}; a1 += vab[5]  * (v2f){w1.y, w1.y};
                a2 += vab[6]  * (v2f){w1.z, w1.z}; a3 += vab[7]  * (v2f){w1.w, w1.w};
                a0 += vab[8]  * (v2f){w2.x, w2.x}; a1 += vab[9]  * (v2f){w2.y, w2.y};
                a2 += vab[10] * (v2f){w2.z, w2.z}; a3 += vab[11] * (v2f){w2.w, w2.w};
                const v2f s = (a0 + a1) + (a2 + a3);
                oA[g] = s.x; oB[g] = s.y;
            }
            *reinterpret_cast<float4*>(&gbufA[wb + j * 4]) =
                make_float4(oA[0], oA[1], oA[2], oA[3]);
            *reinterpret_cast<float4*>(&gbufB[wb + j * 4]) =
                make_float4(oB[0], oB[1], oB[2], oB[3]);
        }
        // ---- same-wave DS ordering (single wave: no barrier) ----
        asm volatile("s_waitcnt lgkmcnt(0)" ::: "memory");
        // ---- consume 16 interleaved A/B step pairs ----
#pragma unroll 4
        for (int i = 0; i < 16; ++i) {
            step(gbufA, xbufA, csA, hA, accSA, i);
            step(gbufB, xbufB, csB, hB, accSB, i);
        }
        if (cn + 1 == warmChunks) {
            accSA = 0.f; accSB = 0.f;          // drop warmup contributions
            if (q == 0) { csA = 0.f; hA = 0.f; } // seg0: exact zero init at s=0
        }
    }

    // ---- group reduction (within 16-lane group; lane0 tree stays clean) ----
    float vA = (jr < 10) ? accSA : 0.f;
    float vB = (jr < 10) ? accSB : 0.f;
#pragma unroll
    for (int off = 1; off <= 8; off <<= 1) {
        vA += __shfl_down(vA, off);
        vB += __shfl_down(vB, off);
    }
    if (jr == 0) {
        P[segA * 512 + d * 256 + b0 + c] = vA;
        P[segB * 512 + d * 256 + b0 + c] = vB;
    }
}

// ---------------------------------------------------------------------------
// Kernel 3: out[b] = sigmoid( sum over 16 segments x 2 directions )
// ---------------------------------------------------------------------------
__global__ __launch_bounds__(256) void final_kernel(const float* __restrict__ P,
                                                    float* __restrict__ out)
{
    const int b = threadIdx.x;
    float v = 0.f;
#pragma unroll
    for (int seg = 0; seg < 16; ++seg)
        v += P[seg * 512 + b] + P[seg * 512 + 256 + b];
    out[b] = frcp(1.f + fexp2(-v * L2E));
}

extern "C" void kernel_launch(void* const* d_in, const int* in_sizes, int n_in,
                              void* d_out, int out_size, void* d_ws, size_t ws_size,
                              hipStream_t stream)
{
    const float* x     = (const float*)d_in[0];
    const float* w4    = (const float*)d_in[1];
    const float* w5    = (const float*)d_in[2];
    const float* w6    = (const float*)d_in[3];
    const float* w7    = (const float*)d_in[4];
    const float* w8    = (const float*)d_in[5];
    const float* Wih_f = (const float*)d_in[6];
    const float* Whh_f = (const float*)d_in[7];
    const float* bih_f = (const float*)d_in[8];
    const float* bhh_f = (const float*)d_in[9];
    const float* Wih_r = (const float*)d_in[10];
    const float* Whh_r = (const float*)d_in[11];
    const float* bih_r = (const float*)d_in[12];
    const float* bhh_r = (const float*)d_in[13];

    // ws layout (fp32): lin [256][4096][16] (64MB) | P[8192] | MMu[1280] | Wp[1280]
    float*    lin = (float*)d_ws;
    float*    P   = lin + (size_t)NBATCH * SEQ * 16;
    unsigned* MMu = (unsigned*)(P + 8192);
    float*    Wpp = (float*)(MMu + 1280);

    wprep_kernel<<<1, 256, 0, stream>>>(Wih_f, bih_f, bhh_f,
                                        Wih_r, bih_r, bhh_r, Wpp, MMu);
    max_kernel<<<4 * NBATCH, 256, 0, stream>>>(x, w4, w5, w6, w7, w8, MMu);
    scatter_kernel<<<4 * NBATCH, 256, 0, stream>>>(x, w4, w5, w6, w7, w8, MMu, lin);
    lstm_kernel<<<1024, 64, 0, stream>>>(lin, Wpp, Whh_f, Whh_r, P);
    final_kernel<<<1, NBATCH, 0, stream>>>(P, (float*)d_out);
}